// Round 5
// baseline (301.732 us; speedup 1.0000x reference)
//
#include <hip/hip_runtime.h>
#include <hip/hip_bf16.h>
#include <cstdint>
#include <cstddef>

#define LAYERS 3
#define EMB 256
#define NB 4096
#define MAXLEN 50

typedef float f32x4 __attribute__((ext_vector_type(4)));
typedef __bf16 bf16x8 __attribute__((ext_vector_type(8)));
typedef unsigned short u16;

static __device__ __forceinline__ u16 f2bf(float f) {
  union { float f; uint32_t u; } v; v.f = f;
  uint32_t r = v.u + 0x7FFFu + ((v.u >> 16) & 1u);
  return (u16)(r >> 16);
}

template <typename T> __device__ __forceinline__ T cvt_out(float v);
template <> __device__ __forceinline__ float cvt_out<float>(float v) { return v; }
template <> __device__ __forceinline__ u16 cvt_out<u16>(float v) { return f2bf(v); }

// ---------------- pack / transpose ----------------
__global__ void pack_bf16(const float* __restrict__ in, u16* __restrict__ out, int n4) {
  int i = blockIdx.x * blockDim.x + threadIdx.x;
  if (i < n4) {
    f32x4 v = reinterpret_cast<const f32x4*>(in)[i];
    ushort4 o;
    o.x = f2bf(v.x); o.y = f2bf(v.y); o.z = f2bf(v.z); o.w = f2bf(v.w);
    reinterpret_cast<ushort4*>(out)[i] = o;
  }
}

// At[n][k] = bf16(A[k][n]), both 4096x4096
__global__ void pack_at(const float* __restrict__ A, u16* __restrict__ At) {
  __shared__ u16 tile[64][65];
  int k0 = blockIdx.y * 64, n0 = blockIdx.x * 64;
  int c = threadIdx.x & 63, r0 = threadIdx.x >> 6;
#pragma unroll
  for (int i = 0; i < 16; i++) {
    int r = r0 + i * 4;
    tile[r][c] = f2bf(A[(size_t)(k0 + r) * NB + n0 + c]);
  }
  __syncthreads();
#pragma unroll
  for (int i = 0; i < 16; i++) {
    int r = r0 + i * 4;
    At[(size_t)(n0 + r) * NB + k0 + c] = tile[c][r];
  }
}

// ---------------- gather + mean pool (1 wave per session, float4/lane) ----------------
__global__ void gather_mean(const float* __restrict__ emb, const int* __restrict__ items,
                            const float* __restrict__ slen, float* __restrict__ acc,
                            u16* __restrict__ xb) {
  int w = threadIdx.x >> 6, lane = threadIdx.x & 63;
  int b = blockIdx.x * 4 + w;
  f32x4 s = {0.f, 0.f, 0.f, 0.f};
  const int* it = items + (size_t)b * MAXLEN;
  for (int l = 0; l < MAXLEN; l++) {
    int idx = it[l];
    if (idx > 0)
      s += *reinterpret_cast<const f32x4*>(emb + (size_t)(idx - 1) * EMB + lane * 4);
  }
  float inv = 1.0f / slen[b];
  s *= inv;
  *reinterpret_cast<f32x4*>(acc + (size_t)b * EMB + lane * 4) = s;
  ushort4 o; o.x = f2bf(s.x); o.y = f2bf(s.y); o.z = f2bf(s.z); o.w = f2bf(s.w);
  *reinterpret_cast<ushort4*>(xb + (size_t)b * EMB + lane * 4) = o;
}

// ================= 256x256 8-wave pipelined GEMM (bf16 -> bf16) =================
// C[M][N] = sum_k Am[m][k] * Bt[n][k]. M,N % 256 == 0, K % 128 == 0, grid % 8 == 0.
// Reads issued ONE PHASE AHEAD of their consuming MFMA cluster (LDS drains under MFMA).
// 3 barriers / K-tile; counted vmcnt(6); staging strictly after region-read certification.
__global__ __launch_bounds__(512, 2) void gemm256(const u16* __restrict__ Am,
                                                  const u16* __restrict__ Bt,
                                                  u16* __restrict__ C,
                                                  int M, int N, int K) {
  __shared__ __align__(16) u16 As[2 * 16384];  // [2][256 rows][64 k] swizzled
  __shared__ __align__(16) u16 Bs[2 * 16384];
  const int tid = threadIdx.x;
  const int lane = tid & 63;
  const int wid = tid >> 6;      // 0..7
  const int wr = wid >> 2;       // 0..1  M-half of this wave
  const int wcn = wid & 3;       // 0..3  N-quarter of this wave
  const int lrow = lane & 15;
  const int lhi = lane >> 4;     // 0..3
  const int sw7 = lrow & 7;      // read-swizzle key (row&7 == lrow&7)
  const int cswz = ((lane & 7) ^ (lane >> 3)) * 8;  // inverse-swizzled source k-offset
  const int srow = wid * 8 + (lane >> 3);           // staging row within a 64-row quarter

  // bijective XCD swizzle (grid.x*grid.y % 8 == 0)
  int bid = blockIdx.y * gridDim.x + blockIdx.x;
  int nwg = gridDim.x * gridDim.y;
  int sw = (bid & 7) * (nwg >> 3) + (bid >> 3);
  int bx = sw % gridDim.x, by = sw / gridDim.x;
  const int row0 = by * 256, col0 = bx * 256;
  const int nkt = K >> 6;

  f32x4 acc[8][4];
#pragma unroll
  for (int mi = 0; mi < 8; mi++)
#pragma unroll
    for (int ni = 0; ni < 4; ni++)
#pragma unroll
      for (int j = 0; j < 4; j++) acc[mi][ni][j] = 0.0f;

  bf16x8 afr[4][2];   // A frags, shared set for QM=0 / QM=1 (WAR forces issue-after-use)
  bf16x8 b0r[2][2];   // B rows wcn*64 + 0..31   (n, kk)
  bf16x8 b1r[2][2];   // B rows wcn*64 + 32..63  (n, kk)

  auto stA = [&](int q, int kb, int p) {
    __builtin_amdgcn_global_load_lds(
        (__attribute__((address_space(1))) void*)(Am + (size_t)(row0 + q * 64 + srow) * K + kb + cswz),
        (__attribute__((address_space(3))) void*)(As + p * 16384 + q * 4096 + wid * 512),
        16, 0, 0);
  };
  auto stB = [&](int q, int kb, int p) {
    __builtin_amdgcn_global_load_lds(
        (__attribute__((address_space(1))) void*)(Bt + (size_t)(col0 + q * 64 + srow) * K + kb + cswz),
        (__attribute__((address_space(3))) void*)(Bs + p * 16384 + q * 4096 + wid * 512),
        16, 0, 0);
  };

#define RD_A(QM, PO)                                                                   \
  _Pragma("unroll") for (int m = 0; m < 4; m++)                                        \
  _Pragma("unroll") for (int kk = 0; kk < 2; kk++) {                                   \
    int row_ = wr * 128 + (QM) * 64 + m * 16 + lrow;                                   \
    afr[m][kk] = *reinterpret_cast<const bf16x8*>(                                     \
        As + (PO) + row_ * 64 + ((kk * 4 + lhi) ^ sw7) * 8);                           \
  }
#define RD_B0(PO)                                                                      \
  _Pragma("unroll") for (int n = 0; n < 2; n++)                                        \
  _Pragma("unroll") for (int kk = 0; kk < 2; kk++) {                                   \
    int row_ = wcn * 64 + n * 16 + lrow;                                               \
    b0r[n][kk] = *reinterpret_cast<const bf16x8*>(                                     \
        Bs + (PO) + row_ * 64 + ((kk * 4 + lhi) ^ sw7) * 8);                           \
  }
#define RD_B1(PO)                                                                      \
  _Pragma("unroll") for (int n = 0; n < 2; n++)                                        \
  _Pragma("unroll") for (int kk = 0; kk < 2; kk++) {                                   \
    int row_ = wcn * 64 + 32 + n * 16 + lrow;                                          \
    b1r[n][kk] = *reinterpret_cast<const bf16x8*>(                                     \
        Bs + (PO) + row_ * 64 + ((kk * 4 + lhi) ^ sw7) * 8);                           \
  }
#define MMA(QM, BREG, QN)                                                              \
  __builtin_amdgcn_s_setprio(1);                                                       \
  _Pragma("unroll") for (int m = 0; m < 4; m++)                                        \
  _Pragma("unroll") for (int n = 0; n < 2; n++)                                        \
  _Pragma("unroll") for (int kk = 0; kk < 2; kk++)                                     \
    acc[(QM) * 4 + m][(QN) * 2 + n] = __builtin_amdgcn_mfma_f32_16x16x32_bf16(         \
        afr[m][kk], BREG[n][kk], acc[(QM) * 4 + m][(QN) * 2 + n], 0, 0, 0);            \
  __builtin_amdgcn_s_setprio(0);

  // prologue: stage K-tiles 0 (buf0) and 1 (buf1); wait tile 0; issue t=0's B0+A0 reads
#pragma unroll
  for (int tt = 0; tt < 2; tt++) {
#pragma unroll
    for (int q = 0; q < 4; q++) stA(q, tt * 64, tt);
#pragma unroll
    for (int q = 0; q < 4; q++) stB(q, tt * 64, tt);
  }
  asm volatile("s_waitcnt vmcnt(8)" ::: "memory");
  __builtin_amdgcn_s_barrier();
  RD_B0(0);
  RD_A(0, 0);

  for (int t = 0; t < nkt; t++) {
    const int p = t & 1;
    const int pO = p * 16384;       // current tile's buffer
    const int qO = (p ^ 1) * 16384; // next tile's buffer
    const int k2 = (t + 2) << 6;
    const bool st = (t + 2) < nkt;
    const bool nx = (t + 1) < nkt;

    // ---- ph0: B1(t) issued; A0,B0(t) certified; stage A q0,q2(t+2); MMA(0,0)
    RD_B1(pO);
    asm volatile("s_waitcnt lgkmcnt(4)" ::: "memory");
    __builtin_amdgcn_s_barrier();
    if (st) { stA(0, k2, p); stA(2, k2, p); }
    MMA(0, b0r, 0)

    // ---- ph1: B1 certified; stage all B(t+2); MMA(0,1); issue A1(t)
    asm volatile("s_waitcnt lgkmcnt(0)" ::: "memory");
    __builtin_amdgcn_s_barrier();
    if (st) { stB(0, k2, p); stB(1, k2, p); stB(2, k2, p); stB(3, k2, p); }
    MMA(0, b1r, 1)
    RD_A(1, pO);

    // ---- ph2: A1 certified + t+1 fully staged (vmcnt 6); stage A q1,q3(t+2);
    //           MMA(1,0); issue B0(t+1) from other buffer
    if (st)      asm volatile("s_waitcnt vmcnt(6) lgkmcnt(0)" ::: "memory");
    else if (nx) asm volatile("s_waitcnt vmcnt(0) lgkmcnt(0)" ::: "memory");
    else         asm volatile("s_waitcnt lgkmcnt(0)" ::: "memory");
    __builtin_amdgcn_s_barrier();
    if (st) { stA(1, k2, p); stA(3, k2, p); }
    MMA(1, b0r, 0)
    if (nx) { RD_B0(qO); }

    // ---- ph3: MMA(1,1) (operands resident); issue A0(t+1); no barrier
    MMA(1, b1r, 1)
    if (nx) { RD_A(0, qO); }
  }

  // epilogue: C write (bf16)
#pragma unroll
  for (int mi = 0; mi < 8; mi++) {
#pragma unroll
    for (int j = 0; j < 4; j++) {
      int r = row0 + wr * 128 + mi * 16 + lhi * 4 + j;
      u16* cp = C + (size_t)r * N + col0 + wcn * 64 + lrow;
#pragma unroll
      for (int ni = 0; ni < 4; ni++) cp[ni * 16] = f2bf(acc[mi][ni][j]);
    }
  }
#undef RD_A
#undef RD_B0
#undef RD_B1
#undef MMA
}

// ---------------- GEMM 128x128 (split-K via blockIdx.z) ----------------
template <typename OUT_T, bool SWZ>
__global__ __launch_bounds__(256, 3) void gemm_bt(const u16* __restrict__ Am,
                                                  const u16* __restrict__ Bt,
                                                  OUT_T* __restrict__ C,
                                                  int M, int N, int K, size_t zstride) {
  __shared__ u16 As[128 * 32];
  __shared__ u16 Bs[128 * 32];
  const int tid = threadIdx.x;
  const int lane = tid & 63;
  const int wid = tid >> 6;
  const int wr = wid >> 1, wc = wid & 1;

  int bx = blockIdx.x, by = blockIdx.y;
  if (SWZ) {
    int nwg = gridDim.x * gridDim.y;
    int bid = by * gridDim.x + bx;
    int cpx = nwg >> 3;
    int sw = (bid & 7) * cpx + (bid >> 3);
    bx = sw % gridDim.x; by = sw / gridDim.x;
  }
  const int row0 = by * 128, col0 = bx * 128;
  const int kslice = K / (int)gridDim.z;
  const int kb = blockIdx.z * kslice, ke = kb + kslice;
  C += (size_t)blockIdx.z * zstride;

  f32x4 acc[4][4];
#pragma unroll
  for (int m = 0; m < 4; m++)
#pragma unroll
    for (int n = 0; n < 4; n++)
#pragma unroll
      for (int j = 0; j < 4; j++) acc[m][n][j] = 0.0f;

  const int lrow = lane & 15;
  const int lko = (lane >> 4) * 8;

  for (int k0 = kb; k0 < ke; k0 += 32) {
#pragma unroll
    for (int inst = 0; inst < 2; inst++) {
      int f = inst * 256 + tid;
      int r = f >> 2, c = (f & 3) * 8;
      const u16* gA = Am + (size_t)(row0 + r) * K + k0 + c;
      const u16* gB = Bt + (size_t)(col0 + r) * K + k0 + c;
      __builtin_amdgcn_global_load_lds(
          (__attribute__((address_space(1))) void*)gA,
          (__attribute__((address_space(3))) void*)(As + (size_t)(inst * 256 + wid * 64) * 8),
          16, 0, 0);
      __builtin_amdgcn_global_load_lds(
          (__attribute__((address_space(1))) void*)gB,
          (__attribute__((address_space(3))) void*)(Bs + (size_t)(inst * 256 + wid * 64) * 8),
          16, 0, 0);
    }
    __syncthreads();

    bf16x8 af[4], bfv[4];
#pragma unroll
    for (int m = 0; m < 4; m++)
      af[m] = *reinterpret_cast<const bf16x8*>(As + (wr * 64 + m * 16 + lrow) * 32 + lko);
#pragma unroll
    for (int n = 0; n < 4; n++)
      bfv[n] = *reinterpret_cast<const bf16x8*>(Bs + (wc * 64 + n * 16 + lrow) * 32 + lko);
#pragma unroll
    for (int m = 0; m < 4; m++)
#pragma unroll
      for (int n = 0; n < 4; n++)
        acc[m][n] = __builtin_amdgcn_mfma_f32_16x16x32_bf16(af[m], bfv[n], acc[m][n], 0, 0, 0);
    __syncthreads();
  }

#pragma unroll
  for (int m = 0; m < 4; m++) {
#pragma unroll
    for (int j = 0; j < 4; j++) {
      int r = row0 + wr * 64 + m * 16 + (lane >> 4) * 4 + j;
      OUT_T* cp = C + (size_t)r * N + col0 + wc * 64 + (lane & 15);
#pragma unroll
      for (int n = 0; n < 4; n++) cp[n * 16] = cvt_out<OUT_T>(acc[m][n][j]);
    }
  }
}

// ---------------- GEMM 64x64 (skinny EMB-sized matmuls) ----------------
__global__ __launch_bounds__(256) void gemm_bt64(const u16* __restrict__ Am,
                                                 const u16* __restrict__ Bt,
                                                 u16* __restrict__ C,
                                                 int M, int N, int K) {
  __shared__ u16 As[64 * 32];
  __shared__ u16 Bs[64 * 32];
  const int tid = threadIdx.x;
  const int lane = tid & 63;
  const int wid = tid >> 6;
  const int wr = wid >> 1, wc = wid & 1;
  const int row0 = blockIdx.y * 64, col0 = blockIdx.x * 64;

  f32x4 acc[2][2];
#pragma unroll
  for (int m = 0; m < 2; m++)
#pragma unroll
    for (int n = 0; n < 2; n++)
#pragma unroll
      for (int j = 0; j < 4; j++) acc[m][n][j] = 0.0f;

  const int lrow = lane & 15;
  const int lko = (lane >> 4) * 8;

  for (int k0 = 0; k0 < K; k0 += 32) {
    int r = tid >> 2, c = (tid & 3) * 8;
    const u16* gA = Am + (size_t)(row0 + r) * K + k0 + c;
    const u16* gB = Bt + (size_t)(col0 + r) * K + k0 + c;
    __builtin_amdgcn_global_load_lds(
        (__attribute__((address_space(1))) void*)gA,
        (__attribute__((address_space(3))) void*)(As + (size_t)(wid * 64) * 8), 16, 0, 0);
    __builtin_amdgcn_global_load_lds(
        (__attribute__((address_space(1))) void*)gB,
        (__attribute__((address_space(3))) void*)(Bs + (size_t)(wid * 64) * 8), 16, 0, 0);
    __syncthreads();

    bf16x8 af[2], bfv[2];
#pragma unroll
    for (int m = 0; m < 2; m++)
      af[m] = *reinterpret_cast<const bf16x8*>(As + (wr * 32 + m * 16 + lrow) * 32 + lko);
#pragma unroll
    for (int n = 0; n < 2; n++)
      bfv[n] = *reinterpret_cast<const bf16x8*>(Bs + (wc * 32 + n * 16 + lrow) * 32 + lko);
#pragma unroll
    for (int m = 0; m < 2; m++)
#pragma unroll
      for (int n = 0; n < 2; n++)
        acc[m][n] = __builtin_amdgcn_mfma_f32_16x16x32_bf16(af[m], bfv[n], acc[m][n], 0, 0, 0);
    __syncthreads();
  }

#pragma unroll
  for (int m = 0; m < 2; m++) {
#pragma unroll
    for (int j = 0; j < 4; j++) {
      int r = row0 + wr * 32 + m * 16 + (lane >> 4) * 4 + j;
      u16* cp = C + (size_t)r * N + col0 + wc * 32 + (lane & 15);
#pragma unroll
      for (int n = 0; n < 2; n++) cp[n * 16] = f2bf(acc[m][n][j]);
    }
  }
}

// ---------------- split-K reduce + row norm + accumulate (+final scale) ----------------
__global__ void norm_acc(const float* __restrict__ zp, size_t zstride, int nsplit,
                         float* __restrict__ acc, u16* __restrict__ xb,
                         float* __restrict__ outp, int fin) {
  int b = blockIdx.x, t = threadIdx.x;
  size_t i = (size_t)b * EMB + t;
  float v = 0.0f;
  for (int s = 0; s < nsplit; s++) v += zp[(size_t)s * zstride + i];
  float s2 = v * v;
#pragma unroll
  for (int o = 32; o > 0; o >>= 1) s2 += __shfl_down(s2, o, 64);
  __shared__ float ws4[4];
  if ((t & 63) == 0) ws4[t >> 6] = s2;
  __syncthreads();
  float tot = ws4[0] + ws4[1] + ws4[2] + ws4[3];
  float rn = 1.0f / fmaxf(sqrtf(tot), 1e-12f);
  if (fin) {
    outp[i] = (acc[i] + v * rn) * 0.25f;
  } else {
    acc[i] += v * rn;
    xb[i] = f2bf(v);
  }
}

// ---------------- launch ----------------
extern "C" void kernel_launch(void* const* d_in, const int* in_sizes, int n_in,
                              void* d_out, int out_size, void* d_ws, size_t ws_size,
                              hipStream_t stream) {
  const float* emb   = (const float*)d_in[0];
  const float* D     = (const float*)d_in[1];
  const float* A     = (const float*)d_in[2];
  const int*   items = (const int*)d_in[3];
  const float* slen  = (const float*)d_in[4];
  const float* w     = (const float*)d_in[5];
  float* out = (float*)d_out;

  char* p = (char*)d_ws;
  u16* Db   = (u16*)p;   p += (size_t)NB * NB * 2;   // dead after big GEMM -> reused as zp
  u16* AbT  = (u16*)p;   p += (size_t)NB * NB * 2;
  u16* DAb  = (u16*)p;   p += (size_t)NB * NB * 2;
  float* accf = (float*)p; p += (size_t)NB * EMB * 4;
  u16* xb   = (u16*)p;   p += (size_t)NB * EMB * 2;
  u16* yT   = (u16*)p;   p += (size_t)EMB * NB * 2;
  u16* wb   = (u16*)p;   p += (size_t)LAYERS * EMB * EMB * 2;
  float* zp = (float*)Db;                            // 8 x [NB][EMB] f32 partials = 32 MB

  pack_bf16<<<NB * NB / 4 / 256, 256, 0, stream>>>(D, Db, NB * NB / 4);
  pack_at<<<dim3(64, 64), 256, 0, stream>>>(A, AbT);
  pack_bf16<<<LAYERS * EMB * EMB / 4 / 256, 256, 0, stream>>>(w, wb, LAYERS * EMB * EMB / 4);

  gather_mean<<<NB / 4, 256, 0, stream>>>(emb, items, slen, accf, xb);

  // DA = D @ A (bf16 out), 256^2 8-wave pipelined GEMM
  gemm256<<<dim3(16, 16), 512, 0, stream>>>(Db, AbT, DAb, NB, NB, NB);

  for (int i = 0; i < LAYERS; i++) {
    // yT[e][b] = sum_f W[e][f] * x[b][f]  (== (x @ W^T)^T), bf16
    gemm_bt64<<<dim3(NB / 64, EMB / 64), 256, 0, stream>>>(wb + (size_t)i * EMB * EMB, xb, yT,
                                                           EMB, NB, EMB);
    // zp[kz][b][e] = partial_k DA[b][j] * yT[e][j], split-K=8, f32 partials
    gemm_bt<float, false><<<dim3(EMB / 128, NB / 128, 8), 256, 0, stream>>>(
        DAb, yT, zp, NB, EMB, NB, (size_t)NB * EMB);
    // v = sum partials; acc += v/||v||; xb = bf16(v); final layer: out = 0.25*(acc+v/||v||)
    norm_acc<<<NB, 256, 0, stream>>>(zp, (size_t)NB * EMB, 8, accf, xb, out, i == LAYERS - 1);
  }
}

// Round 6
// 258.651 us; speedup vs baseline: 1.1666x; 1.1666x over previous
//
#include <hip/hip_runtime.h>
#include <hip/hip_bf16.h>
#include <cstdint>
#include <cstddef>

#define LAYERS 3
#define EMB 256
#define NB 4096
#define MAXLEN 50

typedef float f32x4 __attribute__((ext_vector_type(4)));
typedef __bf16 bf16x8 __attribute__((ext_vector_type(8)));
typedef unsigned short u16;

static __device__ __forceinline__ u16 f2bf(float f) {
  union { float f; uint32_t u; } v; v.f = f;
  uint32_t r = v.u + 0x7FFFu + ((v.u >> 16) & 1u);
  return (u16)(r >> 16);
}

template <typename T> __device__ __forceinline__ T cvt_out(float v);
template <> __device__ __forceinline__ float cvt_out<float>(float v) { return v; }
template <> __device__ __forceinline__ u16 cvt_out<u16>(float v) { return f2bf(v); }

// ---------------- pack to bf16 (row-major, no transpose needed anywhere) ----------------
__global__ void pack_bf16(const float* __restrict__ in, u16* __restrict__ out, int n4) {
  int i = blockIdx.x * blockDim.x + threadIdx.x;
  if (i < n4) {
    f32x4 v = reinterpret_cast<const f32x4*>(in)[i];
    ushort4 o;
    o.x = f2bf(v.x); o.y = f2bf(v.y); o.z = f2bf(v.z); o.w = f2bf(v.w);
    reinterpret_cast<ushort4*>(out)[i] = o;
  }
}

// ---------------- gather + mean pool (1 wave per session, float4/lane) ----------------
__global__ void gather_mean(const float* __restrict__ emb, const int* __restrict__ items,
                            const float* __restrict__ slen, float* __restrict__ acc,
                            u16* __restrict__ xb) {
  int w = threadIdx.x >> 6, lane = threadIdx.x & 63;
  int b = blockIdx.x * 4 + w;
  f32x4 s = {0.f, 0.f, 0.f, 0.f};
  const int* it = items + (size_t)b * MAXLEN;
  for (int l = 0; l < MAXLEN; l++) {
    int idx = it[l];                      // wave-uniform -> broadcast, no divergence
    if (idx > 0)
      s += *reinterpret_cast<const f32x4*>(emb + (size_t)(idx - 1) * EMB + lane * 4);
  }
  float inv = 1.0f / slen[b];
  s *= inv;
  *reinterpret_cast<f32x4*>(acc + (size_t)b * EMB + lane * 4) = s;
  ushort4 o; o.x = f2bf(s.x); o.y = f2bf(s.y); o.z = f2bf(s.z); o.w = f2bf(s.w);
  *reinterpret_cast<ushort4*>(xb + (size_t)b * EMB + lane * 4) = o;
}

// ---------------- GEMM 128x128: C[M][N] = sum_k Am[m][k]*Bt[n][k], split-K via blockIdx.z ----
template <typename OUT_T, bool SWZ>
__global__ __launch_bounds__(256, 3) void gemm_bt(const u16* __restrict__ Am,
                                                  const u16* __restrict__ Bt,
                                                  OUT_T* __restrict__ C,
                                                  int M, int N, int K, size_t zstride) {
  __shared__ u16 As[128 * 32];
  __shared__ u16 Bs[128 * 32];
  const int tid = threadIdx.x;
  const int lane = tid & 63;
  const int wid = tid >> 6;
  const int wr = wid >> 1, wc = wid & 1;  // 2x2 waves, 64x64 each

  int bx = blockIdx.x, by = blockIdx.y;
  if (SWZ) {
    int nwg = gridDim.x * gridDim.y;
    int bid = by * gridDim.x + bx;
    int cpx = nwg >> 3;
    int sw = (bid & 7) * cpx + (bid >> 3);
    bx = sw % gridDim.x; by = sw / gridDim.x;
  }
  const int row0 = by * 128, col0 = bx * 128;
  const int kslice = K / (int)gridDim.z;
  const int kb = blockIdx.z * kslice, ke = kb + kslice;
  C += (size_t)blockIdx.z * zstride;

  f32x4 acc[4][4];
#pragma unroll
  for (int m = 0; m < 4; m++)
#pragma unroll
    for (int n = 0; n < 4; n++)
#pragma unroll
      for (int j = 0; j < 4; j++) acc[m][n][j] = 0.0f;

  const int lrow = lane & 15;
  const int lko = (lane >> 4) * 8;

  for (int k0 = kb; k0 < ke; k0 += 32) {
#pragma unroll
    for (int inst = 0; inst < 2; inst++) {
      int f = inst * 256 + tid;
      int r = f >> 2, c = (f & 3) * 8;
      const u16* gA = Am + (size_t)(row0 + r) * K + k0 + c;
      const u16* gB = Bt + (size_t)(col0 + r) * K + k0 + c;
      __builtin_amdgcn_global_load_lds(
          (__attribute__((address_space(1))) void*)gA,
          (__attribute__((address_space(3))) void*)(As + (size_t)(inst * 256 + wid * 64) * 8),
          16, 0, 0);
      __builtin_amdgcn_global_load_lds(
          (__attribute__((address_space(1))) void*)gB,
          (__attribute__((address_space(3))) void*)(Bs + (size_t)(inst * 256 + wid * 64) * 8),
          16, 0, 0);
    }
    __syncthreads();

    bf16x8 af[4], bfv[4];
#pragma unroll
    for (int m = 0; m < 4; m++)
      af[m] = *reinterpret_cast<const bf16x8*>(As + (wr * 64 + m * 16 + lrow) * 32 + lko);
#pragma unroll
    for (int n = 0; n < 4; n++)
      bfv[n] = *reinterpret_cast<const bf16x8*>(Bs + (wc * 64 + n * 16 + lrow) * 32 + lko);
#pragma unroll
    for (int m = 0; m < 4; m++)
#pragma unroll
      for (int n = 0; n < 4; n++)
        acc[m][n] = __builtin_amdgcn_mfma_f32_16x16x32_bf16(af[m], bfv[n], acc[m][n], 0, 0, 0);
    __syncthreads();
  }

#pragma unroll
  for (int m = 0; m < 4; m++) {
#pragma unroll
    for (int j = 0; j < 4; j++) {
      int r = row0 + wr * 64 + m * 16 + (lane >> 4) * 4 + j;
      OUT_T* cp = C + (size_t)r * N + col0 + wc * 64 + (lane & 15);
#pragma unroll
      for (int n = 0; n < 4; n++) cp[n * 16] = cvt_out<OUT_T>(acc[m][n][j]);
    }
  }
}

// ---------------- GEMM 64x64 (skinny EMB-sized matmuls, K small) ----------------
__global__ __launch_bounds__(256) void gemm_bt64(const u16* __restrict__ Am,
                                                 const u16* __restrict__ Bt,
                                                 u16* __restrict__ C,
                                                 int M, int N, int K) {
  __shared__ u16 As[64 * 32];
  __shared__ u16 Bs[64 * 32];
  const int tid = threadIdx.x;
  const int lane = tid & 63;
  const int wid = tid >> 6;
  const int wr = wid >> 1, wc = wid & 1;  // 2x2 waves, 32x32 each
  const int row0 = blockIdx.y * 64, col0 = blockIdx.x * 64;

  f32x4 acc[2][2];
#pragma unroll
  for (int m = 0; m < 2; m++)
#pragma unroll
    for (int n = 0; n < 2; n++)
#pragma unroll
      for (int j = 0; j < 4; j++) acc[m][n][j] = 0.0f;

  const int lrow = lane & 15;
  const int lko = (lane >> 4) * 8;

  for (int k0 = 0; k0 < K; k0 += 32) {
    int r = tid >> 2, c = (tid & 3) * 8;
    const u16* gA = Am + (size_t)(row0 + r) * K + k0 + c;
    const u16* gB = Bt + (size_t)(col0 + r) * K + k0 + c;
    __builtin_amdgcn_global_load_lds(
        (__attribute__((address_space(1))) void*)gA,
        (__attribute__((address_space(3))) void*)(As + (size_t)(wid * 64) * 8), 16, 0, 0);
    __builtin_amdgcn_global_load_lds(
        (__attribute__((address_space(1))) void*)gB,
        (__attribute__((address_space(3))) void*)(Bs + (size_t)(wid * 64) * 8), 16, 0, 0);
    __syncthreads();

    bf16x8 af[2], bfv[2];
#pragma unroll
    for (int m = 0; m < 2; m++)
      af[m] = *reinterpret_cast<const bf16x8*>(As + (wr * 32 + m * 16 + lrow) * 32 + lko);
#pragma unroll
    for (int n = 0; n < 2; n++)
      bfv[n] = *reinterpret_cast<const bf16x8*>(Bs + (wc * 32 + n * 16 + lrow) * 32 + lko);
#pragma unroll
    for (int m = 0; m < 2; m++)
#pragma unroll
      for (int n = 0; n < 2; n++)
        acc[m][n] = __builtin_amdgcn_mfma_f32_16x16x32_bf16(af[m], bfv[n], acc[m][n], 0, 0, 0);
    __syncthreads();
  }

#pragma unroll
  for (int m = 0; m < 2; m++) {
#pragma unroll
    for (int j = 0; j < 4; j++) {
      int r = row0 + wr * 32 + m * 16 + (lane >> 4) * 4 + j;
      u16* cp = C + (size_t)r * N + col0 + wc * 32 + (lane & 15);
#pragma unroll
      for (int n = 0; n < 2; n++) cp[n * 16] = f2bf(acc[m][n][j]);
    }
  }
}

// ---------------- sum split-K partials -> bf16 (for uT) ----------------
__global__ void uredux(const float* __restrict__ zp, u16* __restrict__ uT,
                       int n4, int nsplit, size_t zstride4) {
  int i = blockIdx.x * blockDim.x + threadIdx.x;
  if (i < n4) {
    f32x4 s = {0.f, 0.f, 0.f, 0.f};
    for (int k = 0; k < nsplit; k++)
      s += reinterpret_cast<const f32x4*>(zp)[(size_t)k * zstride4 + i];
    ushort4 o; o.x = f2bf(s.x); o.y = f2bf(s.y); o.z = f2bf(s.z); o.w = f2bf(s.w);
    reinterpret_cast<ushort4*>(uT)[i] = o;
  }
}

// ---------------- split-K reduce + row norm + accumulate (+final scale) ----------------
__global__ void norm_acc(const float* __restrict__ zp, size_t zstride, int nsplit,
                         float* __restrict__ acc, u16* __restrict__ xb,
                         float* __restrict__ outp, int fin) {
  int b = blockIdx.x, t = threadIdx.x;
  size_t i = (size_t)b * EMB + t;
  float v = 0.0f;
  for (int s = 0; s < nsplit; s++) v += zp[(size_t)s * zstride + i];
  float s2 = v * v;
#pragma unroll
  for (int o = 32; o > 0; o >>= 1) s2 += __shfl_down(s2, o, 64);
  __shared__ float ws4[4];
  if ((t & 63) == 0) ws4[t >> 6] = s2;
  __syncthreads();
  float tot = ws4[0] + ws4[1] + ws4[2] + ws4[3];
  float rn = 1.0f / fmaxf(sqrtf(tot), 1e-12f);
  if (fin) {
    outp[i] = (acc[i] + v * rn) * 0.25f;
  } else {
    acc[i] += v * rn;
    xb[i] = f2bf(v);
  }
}

// ---------------- launch ----------------
// Per layer (associativity rewrite: DA@(xW^T) == D@(A@(xW^T)), 3.2x fewer FLOPs):
//   yT[e][b] = sum_f W[e][f] x[b][f]          (gemm_bt64, bf16)
//   uT[e][b] = sum_j yT[e][j] A[b][j]         (gemm_bt splitK=8 f32 -> uredux -> bf16)
//   z [b][e] = sum_j D[b][j]  uT[e][j]        (gemm_bt splitK=8 f32)
//   acc += z/||z||_row ; xb = bf16(z)         (norm_acc)
extern "C" void kernel_launch(void* const* d_in, const int* in_sizes, int n_in,
                              void* d_out, int out_size, void* d_ws, size_t ws_size,
                              hipStream_t stream) {
  const float* emb   = (const float*)d_in[0];
  const float* D     = (const float*)d_in[1];
  const float* A     = (const float*)d_in[2];
  const int*   items = (const int*)d_in[3];
  const float* slen  = (const float*)d_in[4];
  const float* w     = (const float*)d_in[5];
  float* out = (float*)d_out;

  // workspace carve (~106.5 MB)
  char* p = (char*)d_ws;
  u16* Db   = (u16*)p;   p += (size_t)NB * NB * 2;        // 32 MB  bf16 D row-major
  u16* Ab   = (u16*)p;   p += (size_t)NB * NB * 2;        // 32 MB  bf16 A row-major
  float* zp = (float*)p; p += (size_t)8 * NB * EMB * 4;   // 32 MB  shared splitK partials
  float* accf = (float*)p; p += (size_t)NB * EMB * 4;     // 4 MB
  u16* xb   = (u16*)p;   p += (size_t)NB * EMB * 2;       // 2 MB
  u16* yT   = (u16*)p;   p += (size_t)EMB * NB * 2;       // 2 MB
  u16* uT   = (u16*)p;   p += (size_t)EMB * NB * 2;       // 2 MB
  u16* wb   = (u16*)p;   p += (size_t)LAYERS * EMB * EMB * 2;

  pack_bf16<<<NB * NB / 4 / 256, 256, 0, stream>>>(D, Db, NB * NB / 4);
  pack_bf16<<<NB * NB / 4 / 256, 256, 0, stream>>>(A, Ab, NB * NB / 4);
  pack_bf16<<<LAYERS * EMB * EMB / 4 / 256, 256, 0, stream>>>(w, wb, LAYERS * EMB * EMB / 4);

  gather_mean<<<NB / 4, 256, 0, stream>>>(emb, items, slen, accf, xb);

  for (int i = 0; i < LAYERS; i++) {
    // yT[e][b] = sum_f W[e][f] * x[b][f]
    gemm_bt64<<<dim3(NB / 64, EMB / 64), 256, 0, stream>>>(wb + (size_t)i * EMB * EMB, xb, yT,
                                                           EMB, NB, EMB);
    // uT partials: zp[s][e][b] = partial_j yT[e][j] * A[b][j]   (M=256, N=4096)
    gemm_bt<float, false><<<dim3(NB / 128, EMB / 128, 8), 256, 0, stream>>>(
        yT, Ab, zp, EMB, NB, NB, (size_t)EMB * NB);
    // uT = bf16(sum partials)
    uredux<<<EMB * NB / 4 / 256, 256, 0, stream>>>(zp, uT, EMB * NB / 4, 8,
                                                   (size_t)EMB * NB / 4);
    // z partials: zp[s][b][e] = partial_j D[b][j] * uT[e][j]    (M=4096, N=256)
    gemm_bt<float, false><<<dim3(EMB / 128, NB / 128, 8), 256, 0, stream>>>(
        Db, uT, zp, NB, EMB, NB, (size_t)NB * EMB);
    // v = sum partials; acc += v/||v||; xb = bf16(v); final: out = 0.25*(acc+v/||v||)
    norm_acc<<<NB, 256, 0, stream>>>(zp, (size_t)NB * EMB, 8, accf, xb, out, i == LAYERS - 1);
  }
}